// Round 10
// baseline (113.282 us; speedup 1.0000x reference)
//
#include <hip/hip_runtime.h>
#include <hip/hip_bf16.h>

typedef __attribute__((ext_vector_type(4))) float f32x4;
typedef __attribute__((ext_vector_type(8))) short s16x8;

#define DEVI __device__ __forceinline__

constexpr int S = 512, C = 862, P = 96, H = 128, BATCH = 64;

DEVI short f2bf(float f) {
  unsigned u = __builtin_bit_cast(unsigned, f);
  u += 0x7fffu + ((u >> 16) & 1u);
  return (short)(u >> 16);
}

DEVI unsigned pk2(float a, float b) {
  return (unsigned)(unsigned short)f2bf(a) | ((unsigned)(unsigned short)f2bf(b) << 16);
}

DEVI s16x8 mk8(const float* v) {
  s16x8 r;
#pragma unroll
  for (int i = 0; i < 8; ++i) r[i] = f2bf(v[i]);
  return r;
}

// async global->LDS 16B per lane; lds dest = wave-uniform base (+lane*16 implied)
DEVI void gload16(const void* g, void* l) {
  __builtin_amdgcn_global_load_lds(
      (const __attribute__((address_space(1))) void*)g,
      (__attribute__((address_space(3))) void*)l, 16, 0, 0);
}

// Redistribute lane-local D-tiles (packed bf16 pairs p01/p23, tiles 0..2*NK-1)
// into MFMA B-fragments f[kc], kc = 0..NK-1 (k = kc*32 + l4*8 + i). (r4/r5 verified)
template <int NK>
DEVI void redistN(const unsigned* p01, const unsigned* p23, int sA, int hi,
                  s16x8* f) {
#pragma unroll
  for (int kc = 0; kc < NK; ++kc) {
    unsigned a0 = __shfl(p01[2 * kc], sA),      b0 = __shfl(p01[2 * kc + 1], sA);
    unsigned a1 = __shfl(p23[2 * kc], sA),      b1 = __shfl(p23[2 * kc + 1], sA);
    unsigned a2 = __shfl(p01[2 * kc], sA + 16), b2 = __shfl(p01[2 * kc + 1], sA + 16);
    unsigned a3 = __shfl(p23[2 * kc], sA + 16), b3 = __shfl(p23[2 * kc + 1], sA + 16);
    union { s16x8 v; unsigned u[4]; } t;
    t.u[0] = hi ? b0 : a0;
    t.u[1] = hi ? b1 : a1;
    t.u[2] = hi ? b2 : a2;
    t.u[3] = hi ? b3 : a3;
    f[kc] = t.v;
  }
}

// ---------------- k0: weight conversions (round-5 proven layouts) ----------------
__global__ __launch_bounds__(256) void k0_convert(
    const float* __restrict__ W1, const float* __restrict__ Wp,
    const float* __restrict__ W2, const float* __restrict__ mem,
    short* __restrict__ W1b, short* __restrict__ WpS, short* __restrict__ W2b,
    short* __restrict__ membS, short* __restrict__ memTS) {
  int i = blockIdx.x * 256 + threadIdx.x;
  if (i < 65536) { W1b[i] = f2bf(W1[i]); return; }  // plain [h][s]
  i -= 65536;
  if (i < 16384) {  // Wp [g][h] -> swizzled rows of 128
    int g = i >> 7, h = i & 127;
    WpS[(g << 7) + (h ^ ((g & 7) << 3))] = f2bf(Wp[i]);
    return;
  }
  i -= 16384;
  if (i < 24576) { W2b[i] = f2bf(W2[i]); return; }  // plain [p][256]
  i -= 24576;
  if (i < 65536) {
    int f = i >> 7, d = i & 127;
    short v = f2bf(mem[i]);
    // memb slice-major: slice f>>6 (16KB), row f&63 (128 hw), swizzled
    membS[((f >> 6) << 13) + ((f & 63) << 7) + (d ^ ((f & 7) << 3))] = v;
    // memT slice-major: slice f>>6, row d (64 hw), swizzled
    memTS[((f >> 6) << 13) + (d << 6) + ((f & 63) ^ ((d & 7) << 3))] = v;
  }
}

// ---------------- k1: r1 = sigmoid(x^T W1^T + b1) — barrier-free streaming ----------------
// grid (7, 64) x 256 thr = 4 waves; wave owns 32 c-columns x all 128 h.
// Swapped operands: mfma(A = W1 h-rows from L2, B = x c-columns gathered from HBM
// directly into fragments). No LDS, no barriers — waves free-run, HBM queue stays full.
// D layout: lane(l15,l4) holds [h = t*16 + l4*4 + e][c = cw0 + g*16 + l15].
__global__ __launch_bounds__(256, 2) void k1_repre(
    const float* __restrict__ x, const short* __restrict__ W1b,
    const float* __restrict__ b1, short* __restrict__ R1b) {
  const int b = blockIdx.y;
  const int tid = threadIdx.x, l = tid & 63, w = tid >> 6;
  const int l15 = l & 15, l4 = l >> 4;
  const int cw0 = blockIdx.x * 128 + w * 32;
  if (cw0 >= C) return;  // wave-uniform; no barriers in kernel
  const float* xb = x + (size_t)b * S * C;

  f32x4 acc[2][8];
#pragma unroll
  for (int g = 0; g < 2; ++g)
#pragma unroll
    for (int t = 0; t < 8; ++t) acc[g][t] = (f32x4){0.f, 0.f, 0.f, 0.f};

  // per-lane gather columns (clamped; stores masked later)
  int cc[2];
#pragma unroll
  for (int g = 0; g < 2; ++g) {
    int c = cw0 + g * 16 + l15;
    cc[g] = c < C ? c : C - 1;
  }

#pragma unroll 4
  for (int kc = 0; kc < 16; ++kc) {
    // A-frags: W1 rows (L2-resident after first pass), 64B/row per instr
    s16x8 af[8];
#pragma unroll
    for (int t = 0; t < 8; ++t)
      af[t] = *(const s16x8*)&W1b[(t * 16 + l15) * 512 + kc * 32 + l4 * 8];
#pragma unroll
    for (int g = 0; g < 2; ++g) {
      // B-frag: 8 consecutive-s dwords of column cc[g]
      const float* src = xb + (size_t)(kc * 32 + l4 * 8) * C + cc[g];
      float v[8];
#pragma unroll
      for (int i = 0; i < 8; ++i) v[i] = src[(size_t)i * C];
      s16x8 bx = mk8(v);
#pragma unroll
      for (int t = 0; t < 8; ++t)
        acc[g][t] = __builtin_amdgcn_mfma_f32_16x16x32_bf16(af[t], bx, acc[g][t], 0, 0, 0);
    }
  }

  // epilogue: + b1, sigmoid, packed bf16 pair stores (8B per lane per tile)
#pragma unroll
  for (int g = 0; g < 2; ++g) {
    int c = cw0 + g * 16 + l15;
    if (c < C) {
      short* dst = R1b + ((size_t)b * C + c) * 128;
#pragma unroll
      for (int t = 0; t < 8; ++t) {
        int h0 = t * 16 + l4 * 4;
        f32x4 bq = *(const f32x4*)&b1[h0];
        float s0 = 1.f / (1.f + __expf(-(acc[g][t][0] + bq[0])));
        float s1 = 1.f / (1.f + __expf(-(acc[g][t][1] + bq[1])));
        float s2 = 1.f / (1.f + __expf(-(acc[g][t][2] + bq[2])));
        float s3 = 1.f / (1.f + __expf(-(acc[g][t][3] + bq[3])));
        uint2 pp;
        pp.x = pk2(s0, s1);
        pp.y = pk2(s2, s3);
        *(uint2*)&dst[h0] = pp;
      }
    }
  }
}

// ---------------- k2: fused projector + codebook attention + predictor ----------------
// grid (7, 64), 512 threads = 8 waves x 16 rows = 128 rows/block. (round-7 proven)
__global__ __launch_bounds__(512, 2) void k2_fused(
    const short* __restrict__ R1b, const short* __restrict__ WpS,
    const float* __restrict__ bp, const short* __restrict__ membS,
    const short* __restrict__ memTS, const short* __restrict__ W2b,
    const float* __restrict__ b2, float* __restrict__ out) {
  __shared__ __align__(16) char lds[65536];  // buf p at p*32KB: memb@+0, memT@+16KB
  float* resf = (float*)lds;                 // final [c][p] buffer (49.7KB overlay)

  const int b = blockIdx.y, c0 = blockIdx.x * 128;
  const int valid = (C - c0 < 128) ? (C - c0) : 128;
  const int tid = threadIdx.x, l = tid & 63, w = tid >> 6;  // w: 0..7
  const int l15 = l & 15, l4 = l >> 4;
  const int sA = l15 + 32 * (l4 & 1);
  const int hi = (l4 >> 1) & 1;
  const int xr = (l15 & 7) << 4;   // row-XOR for swizzled frag reads
  const int cb = l4 * 16;          // k-column byte base
  const size_t n0 = (size_t)b * C + c0;

  const int rloc = 16 * w + l15;   // 0..127
  const int rr = rloc < valid ? rloc : valid - 1;

  // ---- prologue: stage Wp -> buf1 (32KB), slice0 -> buf0 (16+16KB) ----
  {
    const char* gwp = (const char*)WpS;
    const char* gmb = (const char*)membS;
    const char* gmt = (const char*)memTS;
#pragma unroll
    for (int i = 0; i < 4; ++i) {
      int o = (w * 4 + i) * 1024;
      gload16(gwp + o + l * 16, lds + 32768 + o);
    }
#pragma unroll
    for (int i = 0; i < 2; ++i) {
      int o = (w * 2 + i) * 1024;
      gload16(gmb + o + l * 16, lds + o);
      gload16(gmt + o + l * 16, lds + 16384 + o);
    }
  }

  // r1 B-fragments (own row, k-octets) — global gather, once
  s16x8 rb[4];
  {
    const short* r1row = R1b + (n0 + rr) * 128;
#pragma unroll
    for (int kc = 0; kc < 4; ++kc)
      rb[kc] = *(const s16x8*)&r1row[kc * 32 + l4 * 8];
  }
  __syncthreads();  // Wp + slice0 staged

  // ---- r2 = r1 @ Wp^T + bp (A = Wp rows from LDS) ----
  unsigned rpk01[8], rpk23[8];
  {
    const char* bufWp = lds + 32768;
#pragma unroll
    for (int gt = 0; gt < 8; ++gt) {
      f32x4 acc = (f32x4){0.f, 0.f, 0.f, 0.f};
#pragma unroll
      for (int kc = 0; kc < 4; ++kc) {
        s16x8 af = *(const s16x8*)(bufWp + (gt * 16 + l15) * 256 + ((kc * 64 + cb) ^ xr));
        acc = __builtin_amdgcn_mfma_f32_16x16x32_bf16(af, rb[kc], acc, 0, 0, 0);
      }
      f32x4 bq = *(const f32x4*)&bp[gt * 16 + l4 * 4];
      rpk01[gt] = pk2(acc[0] + bq[0], acc[1] + bq[1]);
      rpk23[gt] = pk2(acc[2] + bq[2], acc[3] + bq[3]);
    }
  }
  s16x8 r2f[4];
  redistN<4>(rpk01, rpk23, sA, hi, r2f);
  __syncthreads();  // buf1 (Wp) free -> slice1 staging may begin

  float m_run = -1e30f, s_run = 0.f;
  f32x4 oacc[8];
#pragma unroll
  for (int dt = 0; dt < 8; ++dt) oacc[dt] = (f32x4){0.f, 0.f, 0.f, 0.f};

  for (int s = 0; s < 8; ++s) {
    char* bufp = lds + ((s & 1) << 15);
    // issue next slice's staging into the other buffer (overlaps this compute)
    if (s < 7) {
      char* bufn = lds + (((s + 1) & 1) << 15);
      const char* gmb = (const char*)membS + (size_t)(s + 1) * 16384;
      const char* gmt = (const char*)memTS + (size_t)(s + 1) * 16384;
#pragma unroll
      for (int i = 0; i < 2; ++i) {
        int o = (w * 2 + i) * 1024;
        gload16(gmb + o + l * 16, bufn + o);
        gload16(gmt + o + l * 16, bufn + 16384 + o);
      }
    }
    // logits: lane gets S[n=own][f = s*64 + ft*16 + l4*4 + e]
    f32x4 lg[4];
#pragma unroll
    for (int ft = 0; ft < 4; ++ft) {
      lg[ft] = (f32x4){0.f, 0.f, 0.f, 0.f};
#pragma unroll
      for (int kc = 0; kc < 4; ++kc) {
        s16x8 af = *(const s16x8*)(bufp + (ft * 16 + l15) * 256 + ((kc * 64 + cb) ^ xr));
        lg[ft] = __builtin_amdgcn_mfma_f32_16x16x32_bf16(af, r2f[kc], lg[ft], 0, 0, 0);
      }
    }
    // online softmax over this slice's 64 f-values
    float mx = lg[0][0];
#pragma unroll
    for (int ft = 0; ft < 4; ++ft)
#pragma unroll
      for (int e = 0; e < 4; ++e) mx = fmaxf(mx, lg[ft][e]);
    mx = fmaxf(mx, __shfl_xor(mx, 16));
    mx = fmaxf(mx, __shfl_xor(mx, 32));
    float mn = fmaxf(m_run, mx);
    float sc = __expf(m_run - mn);
    float ps = 0.f;
#pragma unroll
    for (int ft = 0; ft < 4; ++ft)
#pragma unroll
      for (int e = 0; e < 4; ++e) {
        float p = __expf(lg[ft][e] - mn);
        lg[ft][e] = p;
        ps += p;
      }
    ps += __shfl_xor(ps, 16);
    ps += __shfl_xor(ps, 32);
    s_run = s_run * sc + ps;
    m_run = mn;
#pragma unroll
    for (int dt = 0; dt < 8; ++dt)
#pragma unroll
      for (int e = 0; e < 4; ++e) oacc[dt][e] *= sc;
    // P -> bf16 B-fragments (k = this slice's 64 f)
    unsigned ppk01[4], ppk23[4];
#pragma unroll
    for (int ft = 0; ft < 4; ++ft) {
      ppk01[ft] = pk2(lg[ft][0], lg[ft][1]);
      ppk23[ft] = pk2(lg[ft][2], lg[ft][3]);
    }
    s16x8 pf[2];
    redistN<2>(ppk01, ppk23, sA, hi, pf);
    // PV: A = memT d-rows from LDS
#pragma unroll
    for (int dt = 0; dt < 8; ++dt) {
#pragma unroll
      for (int kc = 0; kc < 2; ++kc) {
        s16x8 af = *(const s16x8*)(bufp + 16384 + (dt * 16 + l15) * 128 + ((kc * 64 + cb) ^ xr));
        oacc[dt] = __builtin_amdgcn_mfma_f32_16x16x32_bf16(af, pf[kc], oacc[dt], 0, 0, 0);
      }
    }
    __syncthreads();  // slice reads done; next staging drained
  }

  // normalize att-out, pack, redistribute
  s16x8 of[4];
  {
    float inv = 1.f / s_run;
    unsigned opk01[8], opk23[8];
#pragma unroll
    for (int dt = 0; dt < 8; ++dt) {
      opk01[dt] = pk2(oacc[dt][0] * inv, oacc[dt][1] * inv);
      opk23[dt] = pk2(oacc[dt][2] * inv, oacc[dt][3] * inv);
    }
    redistN<4>(opk01, opk23, sA, hi, of);
  }

  // final GEMM: A = W2 p-rows (global, L2-resident), B = [att|r2]
#pragma unroll
  for (int pt = 0; pt < 6; ++pt) {
    f32x4 acc = (f32x4){0.f, 0.f, 0.f, 0.f};
#pragma unroll
    for (int kc = 0; kc < 4; ++kc) {
      s16x8 af = *(const s16x8*)&W2b[(pt * 16 + l15) * 256 + kc * 32 + l4 * 8];
      acc = __builtin_amdgcn_mfma_f32_16x16x32_bf16(af, of[kc], acc, 0, 0, 0);
    }
#pragma unroll
    for (int kc = 0; kc < 4; ++kc) {
      s16x8 af = *(const s16x8*)&W2b[(pt * 16 + l15) * 256 + 128 + kc * 32 + l4 * 8];
      acc = __builtin_amdgcn_mfma_f32_16x16x32_bf16(af, r2f[kc], acc, 0, 0, 0);
    }
    f32x4 bq = *(const f32x4*)&b2[pt * 16 + l4 * 4];
#pragma unroll
    for (int e = 0; e < 4; ++e)
      resf[rloc * 97 + pt * 16 + l4 * 4 + e] = acc[e] + bq[e];
  }
  __syncthreads();
  // coalesced transposed store (256B segments)
  {
    int c = tid & 127, p0 = tid >> 7;
    if (c < valid) {
      float* dst = out + (size_t)b * P * C + c0 + c;
#pragma unroll
      for (int j = 0; j < 24; ++j) {
        int p = p0 + j * 4;
        dst[(size_t)p * C] = resf[c * 97 + p];
      }
    }
  }
}

extern "C" void kernel_launch(void* const* d_in, const int* in_sizes, int n_in,
                              void* d_out, int out_size, void* d_ws, size_t ws_size,
                              hipStream_t stream) {
  const float* x   = (const float*)d_in[0];
  const float* W1  = (const float*)d_in[1];
  const float* b1  = (const float*)d_in[2];
  const float* Wp  = (const float*)d_in[3];
  const float* bpv = (const float*)d_in[4];
  const float* W2  = (const float*)d_in[5];
  const float* b2  = (const float*)d_in[6];
  const float* mem = (const float*)d_in[7];
  char* ws = (char*)d_ws;
  short* W1b   = (short*)(ws);             // 131072 B (plain [h][s])
  short* WpS   = (short*)(ws + 131072);    // 32768 B  (swizzled)
  short* W2b   = (short*)(ws + 163840);    // 49152 B  (plain)
  short* membS = (short*)(ws + 212992);    // 131072 B (slice-major, swizzled)
  short* memTS = (short*)(ws + 344064);    // 131072 B (slice-major, swizzled)
  short* R1b   = (short*)(ws + 475136);    // 14123008 B
  float* outp = (float*)d_out;

  k0_convert<<<672, 256, 0, stream>>>(W1, Wp, W2, mem, W1b, WpS, W2b, membS, memTS);
  dim3 grid1(7, BATCH);
  k1_repre<<<grid1, 256, 0, stream>>>(x, W1b, b1, R1b);
  dim3 grid2(7, BATCH);
  k2_fused<<<grid2, 512, 0, stream>>>(R1b, WpS, bpv, membS, memTS, W2b, b2, outp);
}

// Round 11
// 83.848 us; speedup vs baseline: 1.3510x; 1.3510x over previous
//
#include <hip/hip_runtime.h>
#include <hip/hip_bf16.h>

typedef __attribute__((ext_vector_type(4))) float f32x4;
typedef __attribute__((ext_vector_type(8))) short s16x8;

#define DEVI __device__ __forceinline__

constexpr int S = 512, C = 862, P = 96, H = 128, BATCH = 64;

DEVI short f2bf(float f) {
  unsigned u = __builtin_bit_cast(unsigned, f);
  u += 0x7fffu + ((u >> 16) & 1u);
  return (short)(u >> 16);
}

DEVI unsigned pk2(float a, float b) {
  return (unsigned)(unsigned short)f2bf(a) | ((unsigned)(unsigned short)f2bf(b) << 16);
}

DEVI s16x8 mk8(const float* v) {
  s16x8 r;
#pragma unroll
  for (int i = 0; i < 8; ++i) r[i] = f2bf(v[i]);
  return r;
}

// async global->LDS 16B per lane; lds dest = wave-uniform base (+lane*16 implied)
DEVI void gload16(const void* g, void* l) {
  __builtin_amdgcn_global_load_lds(
      (const __attribute__((address_space(1))) void*)g,
      (__attribute__((address_space(3))) void*)l, 16, 0, 0);
}

// Redistribute lane-local D-tiles (packed bf16 pairs p01/p23, tiles 0..2*NK-1)
// into MFMA B-fragments f[kc], kc = 0..NK-1 (k = kc*32 + l4*8 + i). (r4/r5 verified)
template <int NK>
DEVI void redistN(const unsigned* p01, const unsigned* p23, int sA, int hi,
                  s16x8* f) {
#pragma unroll
  for (int kc = 0; kc < NK; ++kc) {
    unsigned a0 = __shfl(p01[2 * kc], sA),      b0 = __shfl(p01[2 * kc + 1], sA);
    unsigned a1 = __shfl(p23[2 * kc], sA),      b1 = __shfl(p23[2 * kc + 1], sA);
    unsigned a2 = __shfl(p01[2 * kc], sA + 16), b2 = __shfl(p01[2 * kc + 1], sA + 16);
    unsigned a3 = __shfl(p23[2 * kc], sA + 16), b3 = __shfl(p23[2 * kc + 1], sA + 16);
    union { s16x8 v; unsigned u[4]; } t;
    t.u[0] = hi ? b0 : a0;
    t.u[1] = hi ? b1 : a1;
    t.u[2] = hi ? b2 : a2;
    t.u[3] = hi ? b3 : a3;
    f[kc] = t.v;
  }
}

// ---------------- k0: weight conversions (round-5 proven layouts) ----------------
__global__ __launch_bounds__(256) void k0_convert(
    const float* __restrict__ W1, const float* __restrict__ Wp,
    const float* __restrict__ W2, const float* __restrict__ mem,
    short* __restrict__ W1b, short* __restrict__ WpS, short* __restrict__ W2b,
    short* __restrict__ membS, short* __restrict__ memTS) {
  int i = blockIdx.x * 256 + threadIdx.x;
  if (i < 65536) { W1b[i] = f2bf(W1[i]); return; }  // plain [h][s]
  i -= 65536;
  if (i < 16384) {  // Wp [g][h] -> swizzled rows of 128
    int g = i >> 7, h = i & 127;
    WpS[(g << 7) + (h ^ ((g & 7) << 3))] = f2bf(Wp[i]);
    return;
  }
  i -= 16384;
  if (i < 24576) { W2b[i] = f2bf(W2[i]); return; }  // plain [p][256]
  i -= 24576;
  if (i < 65536) {
    int f = i >> 7, d = i & 127;
    short v = f2bf(mem[i]);
    // memb slice-major: slice f>>6 (16KB), row f&63 (128 hw), swizzled
    membS[((f >> 6) << 13) + ((f & 63) << 7) + (d ^ ((f & 7) << 3))] = v;
    // memT slice-major: slice f>>6, row d (64 hw), swizzled
    memTS[((f >> 6) << 13) + (d << 6) + ((f & 63) ^ ((d & 7) << 3))] = v;
  }
}

// ---------------- k12: FUSED repre + projector + codebook attention + predictor ----------------
// grid (7, 64), 512 thr = 8 waves x 16 c-rows. Phase 1: r1 GEMM (r9 staging, r10's
// verified swapped-operand layout: lane holds r1[h][c=own l15]) -> sigmoid -> pack ->
// redistN<4> gives phase-2's rb[4] B-frags IN REGISTERS (no R1b at all).
// Phase 2: round-7-proven k2 body. LDS 64KB reused across phases.
__global__ __launch_bounds__(512, 2) void k12_fused(
    const float* __restrict__ x, const short* __restrict__ W1b,
    const float* __restrict__ b1, const short* __restrict__ WpS,
    const float* __restrict__ bp, const short* __restrict__ membS,
    const short* __restrict__ memTS, const short* __restrict__ W2b,
    const float* __restrict__ b2, float* __restrict__ out) {
  __shared__ __align__(16) char lds[65536];
  // phase 1: xt[2] @ 0/16K (c-major [128][64] bf16), w1t[2] @ 32K/48K ([128][64])
  // phase 2: buf p @ p*32K (memb 16K + memT 16K); Wp @ 32K; resf overlay @ 0
  short* xt0 = (short*)(lds);
  short* xt1 = (short*)(lds + 16384);
  short* w1t0 = (short*)(lds + 32768);
  short* w1t1 = (short*)(lds + 49152);
  float* resf = (float*)lds;

  const int b = blockIdx.y, c0 = blockIdx.x * 128;
  const int valid = (C - c0 < 128) ? (C - c0) : 128;
  const int tid = threadIdx.x, l = tid & 63, w = tid >> 6;  // w: 0..7
  const int l15 = l & 15, l4 = l >> 4;
  const int sA = l15 + 32 * (l4 & 1);
  const int hi = (l4 >> 1) & 1;
  const int xr = (l15 & 7) << 4;   // row-XOR for swizzled frag reads (row&7 = l15&7)
  const int cb = l4 * 16;          // k-column byte base
  const int rloc = 16 * w + l15;   // this lane's c-row, 0..127

  // ================= PHASE 1: r1 = sigmoid(x^T W1^T + b1) =================
  s16x8 rb[4];
  {
    // staging roles: x: (cme=tid&127, octets {o2, o2+4}); W1: (hh=tid>>2, octets {qq,qq+4})
    const int cme = tid & 127, o2 = tid >> 7;
    const bool cv = (c0 + cme) < C;
    const float* xsrc0 = x + (size_t)b * S * C + c0 + cme;
    const int hh = tid >> 2, qq = tid & 3;

    f32x4 acc[8];
#pragma unroll
    for (int t = 0; t < 8; ++t) acc[t] = (f32x4){0.f, 0.f, 0.f, 0.f};

    float xv[2][8];
    s16x8 wv[2];
    // prologue: kt=0
    {
#pragma unroll
      for (int j = 0; j < 2; ++j) {
        const float* src = xsrc0 + (size_t)((o2 + j * 4) * 8) * C;
#pragma unroll
        for (int i = 0; i < 8; ++i) xv[j][i] = cv ? src[(size_t)i * C] : 0.f;
      }
      const short* wsrc = W1b + hh * 512;
      wv[0] = *(const s16x8*)&wsrc[qq * 8];
      wv[1] = *(const s16x8*)&wsrc[(qq + 4) * 8];
    }

    for (int kt = 0; kt < 8; ++kt) {
      short* xt = (kt & 1) ? xt1 : xt0;
      short* w1t = (kt & 1) ? w1t1 : w1t0;
      // write staged regs -> LDS (swizzle: 16B slot ^= row&7)
#pragma unroll
      for (int j = 0; j < 2; ++j)
        *(s16x8*)&xt[cme * 64 + ((o2 + j * 4) ^ (cme & 7)) * 8] = mk8(xv[j]);
      *(s16x8*)&w1t[hh * 64 + (qq ^ (hh & 7)) * 8] = wv[0];
      *(s16x8*)&w1t[hh * 64 + ((qq + 4) ^ (hh & 7)) * 8] = wv[1];
      __syncthreads();
      // 1-deep prefetch of tile kt+1
      if (kt < 7) {
        int kn = kt + 1;
#pragma unroll
        for (int j = 0; j < 2; ++j) {
          const float* src = xsrc0 + (size_t)(kn * 64 + (o2 + j * 4) * 8) * C;
#pragma unroll
          for (int i = 0; i < 8; ++i) xv[j][i] = cv ? src[(size_t)i * C] : 0.f;
        }
        const short* wsrc = W1b + hh * 512 + kn * 64;
        wv[0] = *(const s16x8*)&wsrc[qq * 8];
        wv[1] = *(const s16x8*)&wsrc[(qq + 4) * 8];
      }
      // MFMA: A = W1 h-rows, B = x c-row (own l15) -> D[h][c=l15] (r10-verified layout)
      s16x8 bx[2];
#pragma unroll
      for (int kc = 0; kc < 2; ++kc)
        bx[kc] = *(const s16x8*)&xt[rloc * 64 + ((kc * 4 + l4) ^ (l15 & 7)) * 8];
#pragma unroll
      for (int t = 0; t < 8; ++t) {
#pragma unroll
        for (int kc = 0; kc < 2; ++kc) {
          s16x8 af = *(const s16x8*)&w1t[(t * 16 + l15) * 64 + ((kc * 4 + l4) ^ (l15 & 7)) * 8];
          acc[t] = __builtin_amdgcn_mfma_f32_16x16x32_bf16(af, bx[kc], acc[t], 0, 0, 0);
        }
      }
      if (kt == 7) __syncthreads();  // all phase-1 LDS reads done before reuse
    }

    // bias + sigmoid + pack -> rb (r1 row rloc as B-fragments)
    unsigned p01[8], p23[8];
#pragma unroll
    for (int t = 0; t < 8; ++t) {
      f32x4 bq = *(const f32x4*)&b1[t * 16 + l4 * 4];
      float s0 = 1.f / (1.f + __expf(-(acc[t][0] + bq[0])));
      float s1 = 1.f / (1.f + __expf(-(acc[t][1] + bq[1])));
      float s2 = 1.f / (1.f + __expf(-(acc[t][2] + bq[2])));
      float s3 = 1.f / (1.f + __expf(-(acc[t][3] + bq[3])));
      p01[t] = pk2(s0, s1);
      p23[t] = pk2(s2, s3);
    }
    redistN<4>(p01, p23, sA, hi, rb);
  }

  // ================= PHASE 2: projector + attention + predictor =================
  // stage Wp -> 32K (over w1t), slice0 -> 0..32K (over xt)
  {
    const char* gwp = (const char*)WpS;
    const char* gmb = (const char*)membS;
    const char* gmt = (const char*)memTS;
#pragma unroll
    for (int i = 0; i < 4; ++i) {
      int o = (w * 4 + i) * 1024;
      gload16(gwp + o + l * 16, lds + 32768 + o);
    }
#pragma unroll
    for (int i = 0; i < 2; ++i) {
      int o = (w * 2 + i) * 1024;
      gload16(gmb + o + l * 16, lds + o);
      gload16(gmt + o + l * 16, lds + 16384 + o);
    }
  }
  __syncthreads();  // Wp + slice0 staged

  // ---- r2 = r1 @ Wp^T + bp (A = Wp rows from LDS) ----
  unsigned rpk01[8], rpk23[8];
  {
    const char* bufWp = lds + 32768;
#pragma unroll
    for (int gt = 0; gt < 8; ++gt) {
      f32x4 acc = (f32x4){0.f, 0.f, 0.f, 0.f};
#pragma unroll
      for (int kc = 0; kc < 4; ++kc) {
        s16x8 af = *(const s16x8*)(bufWp + (gt * 16 + l15) * 256 + ((kc * 64 + cb) ^ xr));
        acc = __builtin_amdgcn_mfma_f32_16x16x32_bf16(af, rb[kc], acc, 0, 0, 0);
      }
      f32x4 bq = *(const f32x4*)&bp[gt * 16 + l4 * 4];
      rpk01[gt] = pk2(acc[0] + bq[0], acc[1] + bq[1]);
      rpk23[gt] = pk2(acc[2] + bq[2], acc[3] + bq[3]);
    }
  }
  s16x8 r2f[4];
  redistN<4>(rpk01, rpk23, sA, hi, r2f);
  __syncthreads();  // Wp region free -> slice1 staging may begin

  float m_run = -1e30f, s_run = 0.f;
  f32x4 oacc[8];
#pragma unroll
  for (int dt = 0; dt < 8; ++dt) oacc[dt] = (f32x4){0.f, 0.f, 0.f, 0.f};

  for (int s = 0; s < 8; ++s) {
    char* bufp = lds + ((s & 1) << 15);
    // issue next slice's staging into the other buffer (overlaps this compute)
    if (s < 7) {
      char* bufn = lds + (((s + 1) & 1) << 15);
      const char* gmb = (const char*)membS + (size_t)(s + 1) * 16384;
      const char* gmt = (const char*)memTS + (size_t)(s + 1) * 16384;
#pragma unroll
      for (int i = 0; i < 2; ++i) {
        int o = (w * 2 + i) * 1024;
        gload16(gmb + o + l * 16, bufn + o);
        gload16(gmt + o + l * 16, bufn + 16384 + o);
      }
    }
    // logits: lane gets S[n=own][f = s*64 + ft*16 + l4*4 + e]
    f32x4 lg[4];
#pragma unroll
    for (int ft = 0; ft < 4; ++ft) {
      lg[ft] = (f32x4){0.f, 0.f, 0.f, 0.f};
#pragma unroll
      for (int kc = 0; kc < 4; ++kc) {
        s16x8 af = *(const s16x8*)(bufp + (ft * 16 + l15) * 256 + ((kc * 64 + cb) ^ xr));
        lg[ft] = __builtin_amdgcn_mfma_f32_16x16x32_bf16(af, r2f[kc], lg[ft], 0, 0, 0);
      }
    }
    // online softmax over this slice's 64 f-values
    float mx = lg[0][0];
#pragma unroll
    for (int ft = 0; ft < 4; ++ft)
#pragma unroll
      for (int e = 0; e < 4; ++e) mx = fmaxf(mx, lg[ft][e]);
    mx = fmaxf(mx, __shfl_xor(mx, 16));
    mx = fmaxf(mx, __shfl_xor(mx, 32));
    float mn = fmaxf(m_run, mx);
    float sc = __expf(m_run - mn);
    float ps = 0.f;
#pragma unroll
    for (int ft = 0; ft < 4; ++ft)
#pragma unroll
      for (int e = 0; e < 4; ++e) {
        float p = __expf(lg[ft][e] - mn);
        lg[ft][e] = p;
        ps += p;
      }
    ps += __shfl_xor(ps, 16);
    ps += __shfl_xor(ps, 32);
    s_run = s_run * sc + ps;
    m_run = mn;
#pragma unroll
    for (int dt = 0; dt < 8; ++dt)
#pragma unroll
      for (int e = 0; e < 4; ++e) oacc[dt][e] *= sc;
    // P -> bf16 B-fragments (k = this slice's 64 f)
    unsigned ppk01[4], ppk23[4];
#pragma unroll
    for (int ft = 0; ft < 4; ++ft) {
      ppk01[ft] = pk2(lg[ft][0], lg[ft][1]);
      ppk23[ft] = pk2(lg[ft][2], lg[ft][3]);
    }
    s16x8 pf[2];
    redistN<2>(ppk01, ppk23, sA, hi, pf);
    // PV: A = memT d-rows from LDS
#pragma unroll
    for (int dt = 0; dt < 8; ++dt) {
#pragma unroll
      for (int kc = 0; kc < 2; ++kc) {
        s16x8 af = *(const s16x8*)(bufp + 16384 + (dt * 16 + l15) * 128 + ((kc * 64 + cb) ^ xr));
        oacc[dt] = __builtin_amdgcn_mfma_f32_16x16x32_bf16(af, pf[kc], oacc[dt], 0, 0, 0);
      }
    }
    __syncthreads();  // slice reads done; next staging drained
  }

  // normalize att-out, pack, redistribute
  s16x8 of[4];
  {
    float inv = 1.f / s_run;
    unsigned opk01[8], opk23[8];
#pragma unroll
    for (int dt = 0; dt < 8; ++dt) {
      opk01[dt] = pk2(oacc[dt][0] * inv, oacc[dt][1] * inv);
      opk23[dt] = pk2(oacc[dt][2] * inv, oacc[dt][3] * inv);
    }
    redistN<4>(opk01, opk23, sA, hi, of);
  }

  // final GEMM: A = W2 p-rows (global, L2-resident), B = [att|r2]
#pragma unroll
  for (int pt = 0; pt < 6; ++pt) {
    f32x4 acc = (f32x4){0.f, 0.f, 0.f, 0.f};
#pragma unroll
    for (int kc = 0; kc < 4; ++kc) {
      s16x8 af = *(const s16x8*)&W2b[(pt * 16 + l15) * 256 + kc * 32 + l4 * 8];
      acc = __builtin_amdgcn_mfma_f32_16x16x32_bf16(af, of[kc], acc, 0, 0, 0);
    }
#pragma unroll
    for (int kc = 0; kc < 4; ++kc) {
      s16x8 af = *(const s16x8*)&W2b[(pt * 16 + l15) * 256 + 128 + kc * 32 + l4 * 8];
      acc = __builtin_amdgcn_mfma_f32_16x16x32_bf16(af, r2f[kc], acc, 0, 0, 0);
    }
    f32x4 bq = *(const f32x4*)&b2[pt * 16 + l4 * 4];
#pragma unroll
    for (int e = 0; e < 4; ++e)
      resf[rloc * 97 + pt * 16 + l4 * 4 + e] = acc[e] + bq[e];
  }
  __syncthreads();
  // coalesced transposed store (256B segments)
  {
    int c = tid & 127, p0 = tid >> 7;
    if (c < valid) {
      float* dst = out + (size_t)b * P * C + c0 + c;
#pragma unroll
      for (int j = 0; j < 24; ++j) {
        int p = p0 + j * 4;
        dst[(size_t)p * C] = resf[c * 97 + p];
      }
    }
  }
}

extern "C" void kernel_launch(void* const* d_in, const int* in_sizes, int n_in,
                              void* d_out, int out_size, void* d_ws, size_t ws_size,
                              hipStream_t stream) {
  const float* x   = (const float*)d_in[0];
  const float* W1  = (const float*)d_in[1];
  const float* b1  = (const float*)d_in[2];
  const float* Wp  = (const float*)d_in[3];
  const float* bpv = (const float*)d_in[4];
  const float* W2  = (const float*)d_in[5];
  const float* b2  = (const float*)d_in[6];
  const float* mem = (const float*)d_in[7];
  char* ws = (char*)d_ws;
  short* W1b   = (short*)(ws);             // 131072 B (plain [h][s])
  short* WpS   = (short*)(ws + 131072);    // 32768 B  (swizzled)
  short* W2b   = (short*)(ws + 163840);    // 49152 B  (plain)
  short* membS = (short*)(ws + 212992);    // 131072 B (slice-major, swizzled)
  short* memTS = (short*)(ws + 344064);    // 131072 B (slice-major, swizzled)
  float* outp = (float*)d_out;

  k0_convert<<<672, 256, 0, stream>>>(W1, Wp, W2, mem, W1b, WpS, W2b, membS, memTS);
  dim3 grid(7, BATCH);
  k12_fused<<<grid, 512, 0, stream>>>(x, W1b, b1, WpS, bpv, membS, memTS, W2b, b2, outp);
}

// Round 12
// 83.406 us; speedup vs baseline: 1.3582x; 1.0053x over previous
//
#include <hip/hip_runtime.h>
#include <hip/hip_bf16.h>

typedef __attribute__((ext_vector_type(4))) float f32x4;
typedef __attribute__((ext_vector_type(8))) short s16x8;

#define DEVI __device__ __forceinline__

constexpr int S = 512, C = 862, P = 96, H = 128, BATCH = 64;

DEVI short f2bf(float f) {
  unsigned u = __builtin_bit_cast(unsigned, f);
  u += 0x7fffu + ((u >> 16) & 1u);
  return (short)(u >> 16);
}

DEVI unsigned pk2(float a, float b) {
  return (unsigned)(unsigned short)f2bf(a) | ((unsigned)(unsigned short)f2bf(b) << 16);
}

DEVI s16x8 mk8(const float* v) {
  s16x8 r;
#pragma unroll
  for (int i = 0; i < 8; ++i) r[i] = f2bf(v[i]);
  return r;
}

// async global->LDS 16B per lane; lds dest = wave-uniform base (+lane*16 implied)
DEVI void gload16(const void* g, void* l) {
  __builtin_amdgcn_global_load_lds(
      (const __attribute__((address_space(1))) void*)g,
      (__attribute__((address_space(3))) void*)l, 16, 0, 0);
}

// Redistribute lane-local D-tiles (packed bf16 pairs p01/p23, tiles 0..2*NK-1)
// into MFMA B-fragments f[kc], kc = 0..NK-1 (k = kc*32 + l4*8 + i). (r4/r5 verified)
template <int NK>
DEVI void redistN(const unsigned* p01, const unsigned* p23, int sA, int hi,
                  s16x8* f) {
#pragma unroll
  for (int kc = 0; kc < NK; ++kc) {
    unsigned a0 = __shfl(p01[2 * kc], sA),      b0 = __shfl(p01[2 * kc + 1], sA);
    unsigned a1 = __shfl(p23[2 * kc], sA),      b1 = __shfl(p23[2 * kc + 1], sA);
    unsigned a2 = __shfl(p01[2 * kc], sA + 16), b2 = __shfl(p01[2 * kc + 1], sA + 16);
    unsigned a3 = __shfl(p23[2 * kc], sA + 16), b3 = __shfl(p23[2 * kc + 1], sA + 16);
    union { s16x8 v; unsigned u[4]; } t;
    t.u[0] = hi ? b0 : a0;
    t.u[1] = hi ? b1 : a1;
    t.u[2] = hi ? b2 : a2;
    t.u[3] = hi ? b3 : a3;
    f[kc] = t.v;
  }
}

// ---------------- k0: weight conversions (round-5 proven layouts) ----------------
__global__ __launch_bounds__(256) void k0_convert(
    const float* __restrict__ W1, const float* __restrict__ Wp,
    const float* __restrict__ W2, const float* __restrict__ mem,
    short* __restrict__ W1b, short* __restrict__ WpS, short* __restrict__ W2b,
    short* __restrict__ membS, short* __restrict__ memTS) {
  int i = blockIdx.x * 256 + threadIdx.x;
  if (i < 65536) { W1b[i] = f2bf(W1[i]); return; }  // plain [h][s]
  i -= 65536;
  if (i < 16384) {  // Wp [g][h] -> swizzled rows of 128
    int g = i >> 7, h = i & 127;
    WpS[(g << 7) + (h ^ ((g & 7) << 3))] = f2bf(Wp[i]);
    return;
  }
  i -= 16384;
  if (i < 24576) { W2b[i] = f2bf(W2[i]); return; }  // plain [p][256]
  i -= 24576;
  if (i < 65536) {
    int f = i >> 7, d = i & 127;
    short v = f2bf(mem[i]);
    // memb slice-major: slice f>>6 (16KB), row f&63 (128 hw), swizzled
    membS[((f >> 6) << 13) + ((f & 63) << 7) + (d ^ ((f & 7) << 3))] = v;
    // memT slice-major: slice f>>6, row d (64 hw), swizzled
    memTS[((f >> 6) << 13) + (d << 6) + ((f & 63) ^ ((d & 7) << 3))] = v;
  }
}

// ---------------- k12: FUSED repre + projector + codebook attention + predictor ----------------
// grid (7, 64), 512 thr = 8 waves x 16 c-rows. Phase 1 as r11 (verified).
// Phase 2 PIPELINED: iter i runs logits(i+1) [independent MFMA] alongside PV(i),
// softmax(i+1) after. memb staged 2-ahead, memT 1-ahead, both dbuf. Defer-max (T13).
__global__ __launch_bounds__(512, 4) void k12_fused(
    const float* __restrict__ x, const short* __restrict__ W1b,
    const float* __restrict__ b1, const short* __restrict__ WpS,
    const float* __restrict__ bp, const short* __restrict__ membS,
    const short* __restrict__ memTS, const short* __restrict__ W2b,
    const float* __restrict__ b2, float* __restrict__ out) {
  __shared__ __align__(16) char lds[65536];
  // phase 1: xt[2] @ 0/16K, w1t[2] @ 32K/48K
  // phase 2: memb slot s&1 @ (s&1)*16K; memT slot s&1 @ 32K + (s&1)*16K; Wp transient @ 32K..64K
  short* xt0 = (short*)(lds);
  short* xt1 = (short*)(lds + 16384);
  short* w1t0 = (short*)(lds + 32768);
  short* w1t1 = (short*)(lds + 49152);
  float* resf = (float*)lds;

  const int b = blockIdx.y, c0 = blockIdx.x * 128;
  const int valid = (C - c0 < 128) ? (C - c0) : 128;
  const int tid = threadIdx.x, l = tid & 63, w = tid >> 6;  // w: 0..7
  const int l15 = l & 15, l4 = l >> 4;
  const int sA = l15 + 32 * (l4 & 1);
  const int hi = (l4 >> 1) & 1;
  const int xr = (l15 & 7) << 4;   // row-XOR for swizzled frag reads
  const int cb = l4 * 16;          // k-column byte base
  const int rloc = 16 * w + l15;   // this lane's c-row, 0..127

  // ================= PHASE 1: r1 = sigmoid(x^T W1^T + b1) =================
  s16x8 rb[4];
  {
    const int cme = tid & 127, o2 = tid >> 7;
    const bool cv = (c0 + cme) < C;
    const float* xsrc0 = x + (size_t)b * S * C + c0 + cme;
    const int hh = tid >> 2, qq = tid & 3;

    f32x4 acc[8];
#pragma unroll
    for (int t = 0; t < 8; ++t) acc[t] = (f32x4){0.f, 0.f, 0.f, 0.f};

    float xv[2][8];
    s16x8 wv[2];
    {
#pragma unroll
      for (int j = 0; j < 2; ++j) {
        const float* src = xsrc0 + (size_t)((o2 + j * 4) * 8) * C;
#pragma unroll
        for (int i = 0; i < 8; ++i) xv[j][i] = cv ? src[(size_t)i * C] : 0.f;
      }
      const short* wsrc = W1b + hh * 512;
      wv[0] = *(const s16x8*)&wsrc[qq * 8];
      wv[1] = *(const s16x8*)&wsrc[(qq + 4) * 8];
    }

    for (int kt = 0; kt < 8; ++kt) {
      short* xt = (kt & 1) ? xt1 : xt0;
      short* w1t = (kt & 1) ? w1t1 : w1t0;
#pragma unroll
      for (int j = 0; j < 2; ++j)
        *(s16x8*)&xt[cme * 64 + ((o2 + j * 4) ^ (cme & 7)) * 8] = mk8(xv[j]);
      *(s16x8*)&w1t[hh * 64 + (qq ^ (hh & 7)) * 8] = wv[0];
      *(s16x8*)&w1t[hh * 64 + ((qq + 4) ^ (hh & 7)) * 8] = wv[1];
      __syncthreads();
      if (kt < 7) {
        int kn = kt + 1;
#pragma unroll
        for (int j = 0; j < 2; ++j) {
          const float* src = xsrc0 + (size_t)(kn * 64 + (o2 + j * 4) * 8) * C;
#pragma unroll
          for (int i = 0; i < 8; ++i) xv[j][i] = cv ? src[(size_t)i * C] : 0.f;
        }
        const short* wsrc = W1b + hh * 512 + kn * 64;
        wv[0] = *(const s16x8*)&wsrc[qq * 8];
        wv[1] = *(const s16x8*)&wsrc[(qq + 4) * 8];
      }
      s16x8 bx[2];
#pragma unroll
      for (int kc = 0; kc < 2; ++kc)
        bx[kc] = *(const s16x8*)&xt[rloc * 64 + ((kc * 4 + l4) ^ (l15 & 7)) * 8];
#pragma unroll
      for (int t = 0; t < 8; ++t) {
#pragma unroll
        for (int kc = 0; kc < 2; ++kc) {
          s16x8 af = *(const s16x8*)&w1t[(t * 16 + l15) * 64 + ((kc * 4 + l4) ^ (l15 & 7)) * 8];
          acc[t] = __builtin_amdgcn_mfma_f32_16x16x32_bf16(af, bx[kc], acc[t], 0, 0, 0);
        }
      }
      if (kt == 7) __syncthreads();  // all phase-1 LDS reads done before reuse
    }

    unsigned p01[8], p23[8];
#pragma unroll
    for (int t = 0; t < 8; ++t) {
      f32x4 bq = *(const f32x4*)&b1[t * 16 + l4 * 4];
      float s0 = 1.f / (1.f + __expf(-(acc[t][0] + bq[0])));
      float s1 = 1.f / (1.f + __expf(-(acc[t][1] + bq[1])));
      float s2 = 1.f / (1.f + __expf(-(acc[t][2] + bq[2])));
      float s3 = 1.f / (1.f + __expf(-(acc[t][3] + bq[3])));
      p01[t] = pk2(s0, s1);
      p23[t] = pk2(s2, s3);
    }
    redistN<4>(p01, p23, sA, hi, rb);
  }

  // ================= PHASE 2 (pipelined slice loop) =================
  // prologue staging: Wp -> [32K,64K), memb(0) -> [0,16K)
  {
    const char* gwp = (const char*)WpS;
    const char* gmb = (const char*)membS;
#pragma unroll
    for (int i = 0; i < 4; ++i) {
      int o = (w * 4 + i) * 1024;
      gload16(gwp + o + l * 16, lds + 32768 + o);
    }
#pragma unroll
    for (int i = 0; i < 2; ++i) {
      int o = (w * 2 + i) * 1024;
      gload16(gmb + o + l * 16, lds + o);
    }
  }
  __syncthreads();  // Wp + memb(0) staged

  // r2 = r1 @ Wp^T + bp
  unsigned rpk01[8], rpk23[8];
  {
    const char* bufWp = lds + 32768;
#pragma unroll
    for (int gt = 0; gt < 8; ++gt) {
      f32x4 acc = (f32x4){0.f, 0.f, 0.f, 0.f};
#pragma unroll
      for (int kc = 0; kc < 4; ++kc) {
        s16x8 af = *(const s16x8*)(bufWp + (gt * 16 + l15) * 256 + ((kc * 64 + cb) ^ xr));
        acc = __builtin_amdgcn_mfma_f32_16x16x32_bf16(af, rb[kc], acc, 0, 0, 0);
      }
      f32x4 bq = *(const f32x4*)&bp[gt * 16 + l4 * 4];
      rpk01[gt] = pk2(acc[0] + bq[0], acc[1] + bq[1]);
      rpk23[gt] = pk2(acc[2] + bq[2], acc[3] + bq[3]);
    }
  }
  s16x8 r2f[4];
  redistN<4>(rpk01, rpk23, sA, hi, r2f);

  float m_run, s_run;
  f32x4 oacc[8];
#pragma unroll
  for (int dt = 0; dt < 8; ++dt) oacc[dt] = (f32x4){0.f, 0.f, 0.f, 0.f};
  s16x8 pfb[2][2];

  // slice 0: logits + softmax (from memb slot 0)
  {
    f32x4 lg[4];
#pragma unroll
    for (int ft = 0; ft < 4; ++ft) {
      lg[ft] = (f32x4){0.f, 0.f, 0.f, 0.f};
#pragma unroll
      for (int kc = 0; kc < 4; ++kc) {
        s16x8 af = *(const s16x8*)(lds + (ft * 16 + l15) * 256 + ((kc * 64 + cb) ^ xr));
        lg[ft] = __builtin_amdgcn_mfma_f32_16x16x32_bf16(af, r2f[kc], lg[ft], 0, 0, 0);
      }
    }
    float mx = lg[0][0];
#pragma unroll
    for (int ft = 0; ft < 4; ++ft)
#pragma unroll
      for (int e = 0; e < 4; ++e) mx = fmaxf(mx, lg[ft][e]);
    mx = fmaxf(mx, __shfl_xor(mx, 16));
    mx = fmaxf(mx, __shfl_xor(mx, 32));
    m_run = mx;
    float ps = 0.f;
    unsigned ppk01[4], ppk23[4];
#pragma unroll
    for (int ft = 0; ft < 4; ++ft) {
#pragma unroll
      for (int e = 0; e < 4; ++e) {
        float p = __expf(lg[ft][e] - m_run);
        lg[ft][e] = p;
        ps += p;
      }
      ppk01[ft] = pk2(lg[ft][0], lg[ft][1]);
      ppk23[ft] = pk2(lg[ft][2], lg[ft][3]);
    }
    ps += __shfl_xor(ps, 16);
    ps += __shfl_xor(ps, 32);
    s_run = ps;
    redistN<2>(ppk01, ppk23, sA, hi, pfb[0]);
  }
  __syncthreads();  // all waves done reading Wp region [32K,64K)
  // stage memT(0) -> 32K, memb(1) -> 16K
  {
    const char* gmb = (const char*)membS + 16384;
    const char* gmt = (const char*)memTS;
#pragma unroll
    for (int i = 0; i < 2; ++i) {
      int o = (w * 2 + i) * 1024;
      gload16(gmb + o + l * 16, lds + 16384 + o);
      gload16(gmt + o + l * 16, lds + 32768 + o);
    }
  }

#pragma unroll
  for (int i = 0; i < 7; ++i) {
    __syncthreads();  // drains memT(i) + memb(i+1); prior iter's reads done
    // issue staging: memb(i+2) -> slot(i&1), memT(i+1) -> 32K + slot((i+1)&1)
    if (i < 6) {
      const char* gmb = (const char*)membS + (size_t)(i + 2) * 16384;
#pragma unroll
      for (int j2 = 0; j2 < 2; ++j2) {
        int o = (w * 2 + j2) * 1024;
        gload16(gmb + o + l * 16, lds + ((i & 1) << 14) + o);
      }
    }
    {
      const char* gmt = (const char*)memTS + (size_t)(i + 1) * 16384;
#pragma unroll
      for (int j2 = 0; j2 < 2; ++j2) {
        int o = (w * 2 + j2) * 1024;
        gload16(gmt + o + l * 16, lds + 32768 + (((i + 1) & 1) << 14) + o);
      }
    }
    // logits(i+1) from memb slot((i+1)&1) — independent of PV(i)
    f32x4 lg[4];
    {
      const char* bmb = lds + (((i + 1) & 1) << 14);
#pragma unroll
      for (int ft = 0; ft < 4; ++ft) {
        lg[ft] = (f32x4){0.f, 0.f, 0.f, 0.f};
#pragma unroll
        for (int kc = 0; kc < 4; ++kc) {
          s16x8 af = *(const s16x8*)(bmb + (ft * 16 + l15) * 256 + ((kc * 64 + cb) ^ xr));
          lg[ft] = __builtin_amdgcn_mfma_f32_16x16x32_bf16(af, r2f[kc], lg[ft], 0, 0, 0);
        }
      }
    }
    // PV(i): memT slot(i&1), pfb[i&1]
    {
      const char* bmt = lds + 32768 + ((i & 1) << 14);
#pragma unroll
      for (int dt = 0; dt < 8; ++dt) {
#pragma unroll
        for (int kc = 0; kc < 2; ++kc) {
          s16x8 af = *(const s16x8*)(bmt + (dt * 16 + l15) * 128 + ((kc * 64 + cb) ^ xr));
          oacc[dt] = __builtin_amdgcn_mfma_f32_16x16x32_bf16(af, pfb[i & 1][kc], oacc[dt], 0, 0, 0);
        }
      }
    }
    // softmax(i+1) with defer-max (T13, THR=8)
    {
      float mx = lg[0][0];
#pragma unroll
      for (int ft = 0; ft < 4; ++ft)
#pragma unroll
        for (int e = 0; e < 4; ++e) mx = fmaxf(mx, lg[ft][e]);
      mx = fmaxf(mx, __shfl_xor(mx, 16));
      mx = fmaxf(mx, __shfl_xor(mx, 32));
      if (!__all(mx <= m_run + 8.f)) {
        float mn = fmaxf(m_run, mx);
        float sc = __expf(m_run - mn);
        s_run *= sc;
        m_run = mn;
#pragma unroll
        for (int dt = 0; dt < 8; ++dt)
#pragma unroll
          for (int e = 0; e < 4; ++e) oacc[dt][e] *= sc;
      }
      float ps = 0.f;
      unsigned ppk01[4], ppk23[4];
#pragma unroll
      for (int ft = 0; ft < 4; ++ft) {
#pragma unroll
        for (int e = 0; e < 4; ++e) {
          float p = __expf(lg[ft][e] - m_run);
          lg[ft][e] = p;
          ps += p;
        }
        ppk01[ft] = pk2(lg[ft][0], lg[ft][1]);
        ppk23[ft] = pk2(lg[ft][2], lg[ft][3]);
      }
      ps += __shfl_xor(ps, 16);
      ps += __shfl_xor(ps, 32);
      s_run += ps;
      redistN<2>(ppk01, ppk23, sA, hi, pfb[(i + 1) & 1]);
    }
  }
  __syncthreads();  // drains memT(7)
  // PV(7): memT slot 1, pfb[1]
  {
    const char* bmt = lds + 32768 + 16384;
#pragma unroll
    for (int dt = 0; dt < 8; ++dt) {
#pragma unroll
      for (int kc = 0; kc < 2; ++kc) {
        s16x8 af = *(const s16x8*)(bmt + (dt * 16 + l15) * 128 + ((kc * 64 + cb) ^ xr));
        oacc[dt] = __builtin_amdgcn_mfma_f32_16x16x32_bf16(af, pfb[1][kc], oacc[dt], 0, 0, 0);
      }
    }
  }
  __syncthreads();  // all slice LDS reads done before resf overwrite

  // normalize att-out, pack, redistribute
  s16x8 of[4];
  {
    float inv = 1.f / s_run;
    unsigned opk01[8], opk23[8];
#pragma unroll
    for (int dt = 0; dt < 8; ++dt) {
      opk01[dt] = pk2(oacc[dt][0] * inv, oacc[dt][1] * inv);
      opk23[dt] = pk2(oacc[dt][2] * inv, oacc[dt][3] * inv);
    }
    redistN<4>(opk01, opk23, sA, hi, of);
  }

  // final GEMM: A = W2 p-rows (global, L2-resident), B = [att|r2]
#pragma unroll
  for (int pt = 0; pt < 6; ++pt) {
    f32x4 acc = (f32x4){0.f, 0.f, 0.f, 0.f};
#pragma unroll
    for (int kc = 0; kc < 4; ++kc) {
      s16x8 af = *(const s16x8*)&W2b[(pt * 16 + l15) * 256 + kc * 32 + l4 * 8];
      acc = __builtin_amdgcn_mfma_f32_16x16x32_bf16(af, of[kc], acc, 0, 0, 0);
    }
#pragma unroll
    for (int kc = 0; kc < 4; ++kc) {
      s16x8 af = *(const s16x8*)&W2b[(pt * 16 + l15) * 256 + 128 + kc * 32 + l4 * 8];
      acc = __builtin_amdgcn_mfma_f32_16x16x32_bf16(af, r2f[kc], acc, 0, 0, 0);
    }
    f32x4 bq = *(const f32x4*)&b2[pt * 16 + l4 * 4];
#pragma unroll
    for (int e = 0; e < 4; ++e)
      resf[rloc * 97 + pt * 16 + l4 * 4 + e] = acc[e] + bq[e];
  }
  __syncthreads();
  // coalesced transposed store (256B segments)
  {
    int c = tid & 127, p0 = tid >> 7;
    if (c < valid) {
      float* dst = out + (size_t)b * P * C + c0 + c;
#pragma unroll
      for (int j = 0; j < 24; ++j) {
        int p = p0 + j * 4;
        dst[(size_t)p * C] = resf[c * 97 + p];
      }
    }
  }
}

extern "C" void kernel_launch(void* const* d_in, const int* in_sizes, int n_in,
                              void* d_out, int out_size, void* d_ws, size_t ws_size,
                              hipStream_t stream) {
  const float* x   = (const float*)d_in[0];
  const float* W1  = (const float*)d_in[1];
  const float* b1  = (const float*)d_in[2];
  const float* Wp  = (const float*)d_in[3];
  const float* bpv = (const float*)d_in[4];
  const float* W2  = (const float*)d_in[5];
  const float* b2  = (const float*)d_in[6];
  const float* mem = (const float*)d_in[7];
  char* ws = (char*)d_ws;
  short* W1b   = (short*)(ws);             // 131072 B (plain [h][s])
  short* WpS   = (short*)(ws + 131072);    // 32768 B  (swizzled)
  short* W2b   = (short*)(ws + 163840);    // 49152 B  (plain)
  short* membS = (short*)(ws + 212992);    // 131072 B (slice-major, swizzled)
  short* memTS = (short*)(ws + 344064);    // 131072 B (slice-major, swizzled)
  float* outp = (float*)d_out;

  k0_convert<<<672, 256, 0, stream>>>(W1, Wp, W2, mem, W1b, WpS, W2b, membS, memTS);
  dim3 grid(7, BATCH);
  k12_fused<<<grid, 512, 0, stream>>>(x, W1b, b1, WpS, bpv, membS, memTS, W2b, b2, outp);
}